// Round 1
// baseline (405.953 us; speedup 1.0000x reference)
//
#include <hip/hip_runtime.h>
#include <stdint.h>

#define NROWS 131072
#define BM 64

typedef __attribute__((ext_vector_type(8))) short bf16x8;
typedef __attribute__((ext_vector_type(4))) float f32x4;

struct EncParam { float w; float b; int code; };

__device__ __forceinline__ unsigned short f2bf(float x) {
    union { float f; unsigned u; } v; v.f = x;
    unsigned r = v.u + 0x7FFFu + ((v.u >> 16) & 1u);
    return (unsigned short)(r >> 16);
}

// ws layout:
// [0, 655360)          W1 bf16  [512][640]
// [655360, 1179648)    W2 bf16  [512][512]
// [1179648, +7680)     enc table, 640 * {float w, float b, int code}

__global__ void prep_kernel(
    const float* __restrict__ W1, const float* __restrict__ W2,
    const float* __restrict__ Wsx, const float* __restrict__ bsx,
    const float* __restrict__ Wcx, const float* __restrict__ bcx,
    const float* __restrict__ Wsy, const float* __restrict__ bsy,
    const float* __restrict__ Wcy, const float* __restrict__ bcy,
    const float* __restrict__ Wn, const float* __restrict__ bn,
    unsigned short* __restrict__ w1b, unsigned short* __restrict__ w2b,
    EncParam* __restrict__ enc)
{
    int i = blockIdx.x * blockDim.x + threadIdx.x;
    const int n1 = 512 * 640;
    const int n2 = 512 * 512;
    if (i < n1) w1b[i] = f2bf(W1[i]);
    else if (i < n1 + n2) w2b[i - n1] = f2bf(W2[i - n1]);
    if (i < 640) {
        EncParam e;
        if (i < 512) {
            int srcb = (i < 256) ? 0 : 2;      // from -> {xf,yf}, to -> {xt,yt}
            int q = (i & 255) >> 6;            // 0:sin x  1:cos x  2:sin y  3:cos y
            int j = i & 63;
            if (q == 0)      { e.w = Wsx[j]; e.b = bsx[j]; e.code = 0*8 + srcb + 0; }
            else if (q == 1) { e.w = Wcx[j]; e.b = bcx[j]; e.code = 1*8 + srcb + 0; }
            else if (q == 2) { e.w = Wsy[j]; e.b = bsy[j]; e.code = 0*8 + srcb + 1; }
            else             { e.w = Wcy[j]; e.b = bcy[j]; e.code = 1*8 + srcb + 1; }
        } else {
            int j = i - 512;
            e.w = Wn[j]; e.b = bn[j]; e.code = 2*8 + 4;   // identity, src = numbers
        }
        enc[i] = e;
    }
}

__global__ __launch_bounds__(512) void mlp_kernel(
    const float* __restrict__ pf, const float* __restrict__ pt,
    const float* __restrict__ nm,
    const unsigned short* __restrict__ w1b,
    const unsigned short* __restrict__ w2b,
    const EncParam* __restrict__ enc,
    const float* __restrict__ b1, const float* __restrict__ b2,
    float* __restrict__ out)
{
    // union buffer: feats chunk [64][320] bf16 (row stride 640 B, 40 KB)
    //           then h tile     [64][512] bf16 (row stride 1024 B, 64 KB)
    __shared__ __align__(16) unsigned char lds[65536];

    const int tid  = threadIdx.x;
    const int lane = tid & 63;
    const int wave = tid >> 6;          // 0..7, each owns 64 output cols
    const int l15  = lane & 15;
    const int l4   = lane >> 4;         // 0..3
    const int rowbase = blockIdx.x * BM;
    const int wcol = wave * 64;

    // encode thread mapping: 8 threads per row
    const int erow = tid >> 3;          // 0..63
    const int esub = tid & 7;
    const float v0 = pf[(rowbase + erow) * 2 + 0];
    const float v1 = pf[(rowbase + erow) * 2 + 1];
    const float v2 = pt[(rowbase + erow) * 2 + 0];
    const float v3 = pt[(rowbase + erow) * 2 + 1];
    const float v4 = nm[rowbase + erow];

    f32x4 acc[4][4];
    #pragma unroll
    for (int a = 0; a < 4; ++a)
        #pragma unroll
        for (int b = 0; b < 4; ++b) acc[a][b] = (f32x4)(0.0f);

    // ---------------- layer 1: K = 640 in two 320-wide chunks ----------------
    for (int chunk = 0; chunk < 2; ++chunk) {
        __syncthreads();   // previous chunk fully consumed before overwrite
        for (int k = esub; k < 320; k += 8) {
            EncParam e = enc[chunk * 320 + k];
            int src = e.code & 7;
            int op  = e.code >> 3;
            float xv = (src == 0) ? v0 : (src == 1) ? v1 :
                       (src == 2) ? v2 : (src == 3) ? v3 : v4;
            float a = fmaf(xv, e.w, e.b);
            float r;
            if (op == 0) r = __sinf(a);
            else if (op == 1) r = __cosf(a);
            else r = a;
            *(unsigned short*)(lds + erow * 640 + ((k * 2) ^ ((erow & 7) << 4))) = f2bf(r);
        }
        __syncthreads();

        for (int ks = 0; ks < 10; ++ks) {
            const int kl = ks * 32;
            bf16x8 afr[4];
            #pragma unroll
            for (int rf = 0; rf < 4; ++rf) {
                int row = rf * 16 + l15;
                afr[rf] = *(const bf16x8*)(lds + row * 640 +
                            (((kl + l4 * 8) * 2) ^ ((row & 7) << 4)));
            }
            const int kg = chunk * 320 + kl + l4 * 8;
            bf16x8 bfr[4];
            #pragma unroll
            for (int cf = 0; cf < 4; ++cf)
                bfr[cf] = *(const bf16x8*)(w1b + (wcol + cf * 16 + l15) * 640 + kg);
            #pragma unroll
            for (int cf = 0; cf < 4; ++cf)
                #pragma unroll
                for (int rf = 0; rf < 4; ++rf)
                    acc[rf][cf] = __builtin_amdgcn_mfma_f32_16x16x32_bf16(
                        afr[rf], bfr[cf], acc[rf][cf], 0, 0, 0);
        }
    }

    // ---------------- bias + leaky -> h tile in LDS (bf16) ----------------
    __syncthreads();
    #pragma unroll
    for (int cf = 0; cf < 4; ++cf) {
        const int col = wcol + cf * 16 + l15;
        const float bias = b1[col];
        #pragma unroll
        for (int rf = 0; rf < 4; ++rf) {
            #pragma unroll
            for (int i = 0; i < 4; ++i) {
                float h = acc[rf][cf][i] + bias;
                h = (h >= 0.0f) ? h : 0.01f * h;
                int row = rf * 16 + l4 * 4 + i;
                *(unsigned short*)(lds + row * 1024 + ((col * 2) ^ ((row & 7) << 4))) = f2bf(h);
            }
        }
    }
    __syncthreads();

    // ---------------- layer 2: K = 512 ----------------
    #pragma unroll
    for (int a = 0; a < 4; ++a)
        #pragma unroll
        for (int b = 0; b < 4; ++b) acc[a][b] = (f32x4)(0.0f);

    for (int ks = 0; ks < 16; ++ks) {
        const int kl = ks * 32;
        bf16x8 afr[4];
        #pragma unroll
        for (int rf = 0; rf < 4; ++rf) {
            int row = rf * 16 + l15;
            afr[rf] = *(const bf16x8*)(lds + row * 1024 +
                        (((kl + l4 * 8) * 2) ^ ((row & 7) << 4)));
        }
        bf16x8 bfr[4];
        #pragma unroll
        for (int cf = 0; cf < 4; ++cf)
            bfr[cf] = *(const bf16x8*)(w2b + (wcol + cf * 16 + l15) * 512 + kl + l4 * 8);
        #pragma unroll
        for (int cf = 0; cf < 4; ++cf)
            #pragma unroll
            for (int rf = 0; rf < 4; ++rf)
                acc[rf][cf] = __builtin_amdgcn_mfma_f32_16x16x32_bf16(
                    afr[rf], bfr[cf], acc[rf][cf], 0, 0, 0);
    }

    // ---------------- epilogue: bias + store f32 ----------------
    #pragma unroll
    for (int cf = 0; cf < 4; ++cf) {
        const int col = wcol + cf * 16 + l15;
        const float bias = b2[col];
        #pragma unroll
        for (int rf = 0; rf < 4; ++rf) {
            #pragma unroll
            for (int i = 0; i < 4; ++i) {
                int row = rowbase + rf * 16 + l4 * 4 + i;
                out[row * 512 + col] = acc[rf][cf][i] + bias;
            }
        }
    }
}

extern "C" void kernel_launch(void* const* d_in, const int* in_sizes, int n_in,
                              void* d_out, int out_size, void* d_ws, size_t ws_size,
                              hipStream_t stream)
{
    (void)in_sizes; (void)n_in; (void)out_size; (void)ws_size;
    const float* pf  = (const float*)d_in[0];
    const float* pt  = (const float*)d_in[1];
    const float* nm  = (const float*)d_in[2];
    const float* Wsx = (const float*)d_in[3];
    const float* bsx = (const float*)d_in[4];
    const float* Wcx = (const float*)d_in[5];
    const float* bcx = (const float*)d_in[6];
    const float* Wsy = (const float*)d_in[7];
    const float* bsy = (const float*)d_in[8];
    const float* Wcy = (const float*)d_in[9];
    const float* bcy = (const float*)d_in[10];
    const float* Wn  = (const float*)d_in[11];
    const float* bn  = (const float*)d_in[12];
    const float* W1  = (const float*)d_in[13];
    const float* b1  = (const float*)d_in[14];
    const float* W2  = (const float*)d_in[15];
    const float* b2  = (const float*)d_in[16];

    unsigned char* ws = (unsigned char*)d_ws;
    unsigned short* w1b = (unsigned short*)(ws);
    unsigned short* w2b = (unsigned short*)(ws + 512 * 640 * 2);
    EncParam* enc = (EncParam*)(ws + 512 * 640 * 2 + 512 * 512 * 2);

    const int prep_threads = 512 * 640 + 512 * 512;
    prep_kernel<<<(prep_threads + 255) / 256, 256, 0, stream>>>(
        W1, W2, Wsx, bsx, Wcx, bcx, Wsy, bsy, Wcy, bcy, Wn, bn, w1b, w2b, enc);

    mlp_kernel<<<NROWS / BM, 512, 0, stream>>>(
        pf, pt, nm, w1b, w2b, enc, b1, b2, (float*)d_out);
}

// Round 2
// 338.352 us; speedup vs baseline: 1.1998x; 1.1998x over previous
//
#include <hip/hip_runtime.h>
#include <stdint.h>

#define NROWS 131072
#define BM 64

typedef __attribute__((ext_vector_type(8))) short bf16x8;
typedef __attribute__((ext_vector_type(4))) float f32x4;
typedef __attribute__((ext_vector_type(4))) int i32x4;
typedef __attribute__((ext_vector_type(2))) unsigned int u32x2;

__device__ __forceinline__ unsigned f2bf(float x) {
    union { float f; unsigned u; } v; v.f = x;
    unsigned r = v.u + 0x7FFFu + ((v.u >> 16) & 1u);
    return r >> 16;
}

// ws layout:
// [0, 655360)            W1 bf16 [512][640]
// [655360, 1179648)      W2 bf16 [512][512]
// [1179648, +2560)       wf[640] f32 (encode weights, cos folded to sin)
// [1182208, +2560)       bfv[640] f32 (encode biases, +pi/2 for cos)

__global__ void prep_kernel(
    const float* __restrict__ W1, const float* __restrict__ W2,
    const float* __restrict__ Wsx, const float* __restrict__ bsx,
    const float* __restrict__ Wcx, const float* __restrict__ bcx,
    const float* __restrict__ Wsy, const float* __restrict__ bsy,
    const float* __restrict__ Wcy, const float* __restrict__ bcy,
    const float* __restrict__ Wn, const float* __restrict__ bn,
    unsigned short* __restrict__ w1b, unsigned short* __restrict__ w2b,
    float* __restrict__ wf, float* __restrict__ bfv)
{
    int i = blockIdx.x * blockDim.x + threadIdx.x;
    const int n1 = 512 * 640;
    const int n2 = 512 * 512;
    if (i < n1) w1b[i] = (unsigned short)f2bf(W1[i]);
    else if (i < n1 + n2) w2b[i - n1] = (unsigned short)f2bf(W2[i - n1]);
    if (i < 640) {
        const float HPI = 1.57079632679489662f;
        float w, b;
        if (i < 512) {
            int j = i & 63, q = (i >> 6) & 3;
            if      (q == 0) { w = Wsx[j]; b = bsx[j]; }
            else if (q == 1) { w = Wcx[j]; b = bcx[j] + HPI; }  // cos(a)=sin(a+pi/2)
            else if (q == 2) { w = Wsy[j]; b = bsy[j]; }
            else             { w = Wcy[j]; b = bcy[j] + HPI; }
        } else { w = Wn[i - 512]; b = bn[i - 512]; }
        wf[i] = w; bfv[i] = b;
    }
}

// feats LDS: [64][640] bf16, row stride 1280 B, byte XOR ((row&7)<<4). 80 KB.
// h LDS (aliased): [64][512] bf16, row stride 1024 B, same XOR.
#define FSTR 1280
#define HSTR 1024

__global__ __launch_bounds__(512, 4) void mlp_kernel(
    const float* __restrict__ pf, const float* __restrict__ pt,
    const float* __restrict__ nm,
    const unsigned short* __restrict__ w1b,
    const unsigned short* __restrict__ w2b,
    const float* __restrict__ wf, const float* __restrict__ bfv,
    const float* __restrict__ b1, const float* __restrict__ b2,
    float* __restrict__ out)
{
    __shared__ __align__(16) unsigned char lds[81920];

    const int tid  = threadIdx.x;
    const int lane = tid & 63;
    const int wave = tid >> 6;          // 0..7, each owns 64 output cols
    const int l15  = lane & 15;
    const int l4   = lane >> 4;         // 0..3
    const int rowbase = blockIdx.x * BM;
    const int wcol = wave * 64;
    const unsigned swz = (unsigned)((l15 & 7) << 4);

    // W1 fragment base: A-operand row = out col (wcol+cf*16+l15), k = ks*32+l4*8
    const unsigned short* w1p = w1b + (wcol + l15) * 640 + l4 * 8;
    const unsigned short* w2p = w2b + (wcol + l15) * 512 + l4 * 8;

    bf16x8 bA[4], bB[4];
    // prefetch W1 frags for ks=0 (hidden under encode phase)
    #pragma unroll
    for (int cf = 0; cf < 4; ++cf)
        bA[cf] = *(const bf16x8*)(w1p + cf * (16 * 640));

    // ---------------- encode: 8 threads/row, 80 feats each ----------------
    {
        const int erow = tid >> 3;
        const int esub = tid & 7;
        const int grow = rowbase + erow;
        const float v0 = pf[grow * 2 + 0];
        const float v1 = pf[grow * 2 + 1];
        const float v2 = pt[grow * 2 + 0];
        const float v3 = pt[grow * 2 + 1];
        const float v4 = nm[grow];
        const unsigned eswz = (unsigned)((erow & 7) << 4);
        const int k0 = esub * 80;
        #pragma unroll
        for (int j = 0; j < 10; ++j) {
            const int k = k0 + j * 8;
            // src/op uniform within an 8-pack (segments are 64-aligned)
            const int op = (k >= 512);
            const int srcsel = op ? 4 : (((k >> 8) << 1) | ((k >> 7) & 1));
            const float xv = (srcsel == 0) ? v0 : (srcsel == 1) ? v1 :
                             (srcsel == 2) ? v2 : (srcsel == 3) ? v3 : v4;
            const f32x4 w0 = *(const f32x4*)(wf + k);
            const f32x4 w1v = *(const f32x4*)(wf + k + 4);
            const f32x4 c0 = *(const f32x4*)(bfv + k);
            const f32x4 c1 = *(const f32x4*)(bfv + k + 4);
            float r[8];
            #pragma unroll
            for (int t = 0; t < 4; ++t) {
                float a0 = fmaf(xv, w0[t], c0[t]);
                float a1 = fmaf(xv, w1v[t], c1[t]);
                r[t]     = op ? a0 : __sinf(a0);
                r[t + 4] = op ? a1 : __sinf(a1);
            }
            i32x4 pk;
            pk.x = (int)(f2bf(r[0]) | (f2bf(r[1]) << 16));
            pk.y = (int)(f2bf(r[2]) | (f2bf(r[3]) << 16));
            pk.z = (int)(f2bf(r[4]) | (f2bf(r[5]) << 16));
            pk.w = (int)(f2bf(r[6]) | (f2bf(r[7]) << 16));
            *(i32x4*)(lds + erow * FSTR + (((unsigned)(k * 2)) ^ eswz)) = pk;
        }
    }

    f32x4 acc[4][4];
    #pragma unroll
    for (int a = 0; a < 4; ++a)
        #pragma unroll
        for (int b = 0; b < 4; ++b) acc[a][b] = (f32x4)(0.0f);

    __syncthreads();

    // ---------------- layer 1: K=640, 20 ks-steps, W-frag prefetch ----------------
#define COMPUTE1(BF, KS) do {                                                      \
        _Pragma("unroll")                                                          \
        for (int rf = 0; rf < 4; ++rf) {                                           \
            bf16x8 af = *(const bf16x8*)(lds + (rf * 16 + l15) * FSTR +            \
                          (((unsigned)((KS) * 64 + l4 * 16)) ^ swz));              \
            _Pragma("unroll")                                                      \
            for (int cf = 0; cf < 4; ++cf)                                         \
                acc[rf][cf] = __builtin_amdgcn_mfma_f32_16x16x32_bf16(             \
                    BF[cf], af, acc[rf][cf], 0, 0, 0);                             \
        }                                                                          \
    } while (0)

    for (int ks2 = 0; ks2 < 10; ++ks2) {
        const int ksA = 2 * ks2;
        #pragma unroll
        for (int cf = 0; cf < 4; ++cf)
            bB[cf] = *(const bf16x8*)(w1p + cf * (16 * 640) + (ksA + 1) * 32);
        COMPUTE1(bA, ksA);
        const int nk = (ksA + 2 < 20) ? (ksA + 2) : 19;
        #pragma unroll
        for (int cf = 0; cf < 4; ++cf)
            bA[cf] = *(const bf16x8*)(w1p + cf * (16 * 640) + nk * 32);
        COMPUTE1(bB, ksA + 1);
    }

    __syncthreads();   // all feats reads done; h may alias feats

    // prefetch W2 frags for ks=0 (hidden under h epilogue)
    #pragma unroll
    for (int cf = 0; cf < 4; ++cf)
        bA[cf] = *(const bf16x8*)(w2p + cf * (16 * 512));

    // ---------------- bias + leaky -> h (bf16, vectorized 8B writes) ----------------
    #pragma unroll
    for (int cf = 0; cf < 4; ++cf) {
        const int colb = wcol + cf * 16 + l4 * 4;
        const f32x4 bb = *(const f32x4*)(b1 + colb);
        #pragma unroll
        for (int rf = 0; rf < 4; ++rf) {
            const int row = rf * 16 + l15;
            float h0 = acc[rf][cf][0] + bb[0];
            float h1 = acc[rf][cf][1] + bb[1];
            float h2 = acc[rf][cf][2] + bb[2];
            float h3 = acc[rf][cf][3] + bb[3];
            h0 = (h0 >= 0.f) ? h0 : 0.01f * h0;
            h1 = (h1 >= 0.f) ? h1 : 0.01f * h1;
            h2 = (h2 >= 0.f) ? h2 : 0.01f * h2;
            h3 = (h3 >= 0.f) ? h3 : 0.01f * h3;
            u32x2 pk;
            pk.x = f2bf(h0) | (f2bf(h1) << 16);
            pk.y = f2bf(h2) | (f2bf(h3) << 16);
            *(u32x2*)(lds + row * HSTR + (((unsigned)(colb * 2)) ^ swz)) = pk;
        }
    }

    __syncthreads();

    // ---------------- layer 2: K=512, 16 ks-steps ----------------
    #pragma unroll
    for (int a = 0; a < 4; ++a)
        #pragma unroll
        for (int b = 0; b < 4; ++b) acc[a][b] = (f32x4)(0.0f);

#define COMPUTE2(BF, KS) do {                                                      \
        _Pragma("unroll")                                                          \
        for (int rf = 0; rf < 4; ++rf) {                                           \
            bf16x8 hf = *(const bf16x8*)(lds + (rf * 16 + l15) * HSTR +            \
                          (((unsigned)((KS) * 64 + l4 * 16)) ^ swz));              \
            _Pragma("unroll")                                                      \
            for (int cf = 0; cf < 4; ++cf)                                         \
                acc[rf][cf] = __builtin_amdgcn_mfma_f32_16x16x32_bf16(             \
                    BF[cf], hf, acc[rf][cf], 0, 0, 0);                             \
        }                                                                          \
    } while (0)

    for (int ks2 = 0; ks2 < 8; ++ks2) {
        const int ksA = 2 * ks2;
        #pragma unroll
        for (int cf = 0; cf < 4; ++cf)
            bB[cf] = *(const bf16x8*)(w2p + cf * (16 * 512) + (ksA + 1) * 32);
        COMPUTE2(bA, ksA);
        const int nk = (ksA + 2 < 16) ? (ksA + 2) : 15;
        #pragma unroll
        for (int cf = 0; cf < 4; ++cf)
            bA[cf] = *(const bf16x8*)(w2p + cf * (16 * 512) + nk * 32);
        COMPUTE2(bB, ksA + 1);
    }

    // ---------------- epilogue: bias + float4 stores ----------------
    #pragma unroll
    for (int cf = 0; cf < 4; ++cf) {
        const int colb = wcol + cf * 16 + l4 * 4;
        const f32x4 bb = *(const f32x4*)(b2 + colb);
        #pragma unroll
        for (int rf = 0; rf < 4; ++rf) {
            const int row = rowbase + rf * 16 + l15;
            f32x4 o = acc[rf][cf] + bb;
            *(f32x4*)(out + row * 512 + colb) = o;
        }
    }
}

extern "C" void kernel_launch(void* const* d_in, const int* in_sizes, int n_in,
                              void* d_out, int out_size, void* d_ws, size_t ws_size,
                              hipStream_t stream)
{
    (void)in_sizes; (void)n_in; (void)out_size; (void)ws_size;
    const float* pf  = (const float*)d_in[0];
    const float* pt  = (const float*)d_in[1];
    const float* nm  = (const float*)d_in[2];
    const float* Wsx = (const float*)d_in[3];
    const float* bsx = (const float*)d_in[4];
    const float* Wcx = (const float*)d_in[5];
    const float* bcx = (const float*)d_in[6];
    const float* Wsy = (const float*)d_in[7];
    const float* bsy = (const float*)d_in[8];
    const float* Wcy = (const float*)d_in[9];
    const float* bcy = (const float*)d_in[10];
    const float* Wn  = (const float*)d_in[11];
    const float* bn  = (const float*)d_in[12];
    const float* W1  = (const float*)d_in[13];
    const float* b1  = (const float*)d_in[14];
    const float* W2  = (const float*)d_in[15];
    const float* b2  = (const float*)d_in[16];

    unsigned char* ws = (unsigned char*)d_ws;
    unsigned short* w1b = (unsigned short*)(ws);
    unsigned short* w2b = (unsigned short*)(ws + 512 * 640 * 2);
    float* wf  = (float*)(ws + 512 * 640 * 2 + 512 * 512 * 2);
    float* bfv = (float*)(ws + 512 * 640 * 2 + 512 * 512 * 2 + 640 * 4);

    const int prep_threads = 512 * 640 + 512 * 512;
    prep_kernel<<<(prep_threads + 255) / 256, 256, 0, stream>>>(
        W1, W2, Wsx, bsx, Wcx, bcx, Wsy, bsy, Wcy, bcy, Wn, bn, w1b, w2b, wf, bfv);

    mlp_kernel<<<NROWS / BM, 512, 0, stream>>>(
        pf, pt, nm, w1b, w2b, wf, bfv, b1, b2, (float*)d_out);
}

// Round 3
// 297.001 us; speedup vs baseline: 1.3668x; 1.1392x over previous
//
#include <hip/hip_runtime.h>
#include <stdint.h>

#define NROWS 131072
#define BM 64
#define NK1 20
#define NK2 16

typedef __attribute__((ext_vector_type(8))) short bf16x8;
typedef __attribute__((ext_vector_type(4))) float f32x4;
typedef __attribute__((ext_vector_type(4))) int i32x4;
typedef __attribute__((ext_vector_type(2))) unsigned int u32x2;

__device__ __forceinline__ unsigned f2bf(float x) {
    union { float f; unsigned u; } v; v.f = x;
    unsigned r = v.u + 0x7FFFu + ((v.u >> 16) & 1u);
    return r >> 16;
}

// ws layout:
// [0, 655360)            W1 bf16 [512][640]
// [655360, 1179648)      W2 bf16 [512][512]
// [1179648, +2560)       wf[640] f32 (encode weights, cos folded to sin)
// [1182208, +2560)       bfv[640] f32 (encode biases, +pi/2 for cos)

__global__ void prep_kernel(
    const float* __restrict__ W1, const float* __restrict__ W2,
    const float* __restrict__ Wsx, const float* __restrict__ bsx,
    const float* __restrict__ Wcx, const float* __restrict__ bcx,
    const float* __restrict__ Wsy, const float* __restrict__ bsy,
    const float* __restrict__ Wcy, const float* __restrict__ bcy,
    const float* __restrict__ Wn, const float* __restrict__ bn,
    unsigned short* __restrict__ w1b, unsigned short* __restrict__ w2b,
    float* __restrict__ wf, float* __restrict__ bfv)
{
    int i = blockIdx.x * blockDim.x + threadIdx.x;
    const int n1 = 512 * 640;
    const int n2 = 512 * 512;
    if (i < n1) w1b[i] = (unsigned short)f2bf(W1[i]);
    else if (i < n1 + n2) w2b[i - n1] = (unsigned short)f2bf(W2[i - n1]);
    if (i < 640) {
        const float HPI = 1.57079632679489662f;
        float w, b;
        if (i < 512) {
            int j = i & 63, q = (i >> 6) & 3;
            if      (q == 0) { w = Wsx[j]; b = bsx[j]; }
            else if (q == 1) { w = Wcx[j]; b = bcx[j] + HPI; }
            else if (q == 2) { w = Wsy[j]; b = bsy[j]; }
            else             { w = Wcy[j]; b = bcy[j] + HPI; }
        } else { w = Wn[i - 512]; b = bn[i - 512]; }
        wf[i] = w; bfv[i] = b;
    }
}

// LDS map (bytes):
// [0, 81920)         feats [64][640] bf16, stride 1280, byte-XOR ((row&7)<<4)
//                    h [64][512] bf16, stride 1024, same XOR (aliased)
// [81920, 114688)    Wbuf0 [512][32] bf16 (row stride 64 B)
// [114688, 147456)   Wbuf1
#define FSTR 1280
#define HSTR 1024
#define WOFF 81920
#define WBUFSZ 32768

// Stage one [512][32] W k-slice into LDS via global_load_lds (16 B/lane).
// LDS dest is wave-uniform base; HW adds lane*16. Global src is per-lane.
__device__ __forceinline__ void stage_w(const unsigned short* __restrict__ Wg, int K,
                                        int ks, unsigned char* ldsb, int wave, int lane)
{
    const unsigned short* src =
        Wg + (size_t)(wave * 64 + (lane >> 2)) * K + ks * 32 + (lane & 3) * 8;
    #pragma unroll
    for (int i = 0; i < 4; ++i) {
        __builtin_amdgcn_global_load_lds(
            (const __attribute__((address_space(1))) unsigned int*)(src + i * 16 * K),
            (__attribute__((address_space(3))) unsigned int*)(ldsb + (wave * 64 + i * 16) * 64),
            16, 0, 0);
    }
}

__global__ __launch_bounds__(512, 2) void mlp_kernel(
    const float* __restrict__ pf, const float* __restrict__ pt,
    const float* __restrict__ nm,
    const unsigned short* __restrict__ w1b,
    const unsigned short* __restrict__ w2b,
    const float* __restrict__ wf, const float* __restrict__ bfv,
    const float* __restrict__ b1, const float* __restrict__ b2,
    float* __restrict__ out)
{
    __shared__ __align__(16) unsigned char lds[WOFF + 2 * WBUFSZ];

    const int tid  = threadIdx.x;
    const int lane = tid & 63;
    const int wave = tid >> 6;          // 0..7, each owns 64 output cols
    const int l15  = lane & 15;
    const int l4   = lane >> 4;         // 0..3
    const int rowbase = blockIdx.x * BM;
    const int wcol = wave * 64;
    const unsigned swz = (unsigned)((l15 & 7) << 4);

    unsigned char* ldsw0 = lds + WOFF;
    unsigned char* ldsw1 = lds + WOFF + WBUFSZ;

    // issue W1 slices 0,1 — they complete under the encode phase
    stage_w(w1b, 640, 0, ldsw0, wave, lane);
    stage_w(w1b, 640, 1, ldsw1, wave, lane);

    // ---------------- encode: 8 threads/row, 80 feats each ----------------
    {
        const int erow = tid >> 3;
        const int esub = tid & 7;
        const int grow = rowbase + erow;
        const float v0 = pf[grow * 2 + 0];
        const float v1 = pf[grow * 2 + 1];
        const float v2 = pt[grow * 2 + 0];
        const float v3 = pt[grow * 2 + 1];
        const float v4 = nm[grow];
        const unsigned eswz = (unsigned)((erow & 7) << 4);
        const int k0 = esub * 80;
        #pragma unroll
        for (int j = 0; j < 10; ++j) {
            const int k = k0 + j * 8;
            const int op = (k >= 512);
            const int srcsel = op ? 4 : (((k >> 8) << 1) | ((k >> 7) & 1));
            const float xv = (srcsel == 0) ? v0 : (srcsel == 1) ? v1 :
                             (srcsel == 2) ? v2 : (srcsel == 3) ? v3 : v4;
            const f32x4 w0 = *(const f32x4*)(wf + k);
            const f32x4 w1v = *(const f32x4*)(wf + k + 4);
            const f32x4 c0 = *(const f32x4*)(bfv + k);
            const f32x4 c1 = *(const f32x4*)(bfv + k + 4);
            float r[8];
            #pragma unroll
            for (int t = 0; t < 4; ++t) {
                float a0 = fmaf(xv, w0[t], c0[t]);
                float a1 = fmaf(xv, w1v[t], c1[t]);
                r[t]     = op ? a0 : __sinf(a0);
                r[t + 4] = op ? a1 : __sinf(a1);
            }
            i32x4 pk;
            pk.x = (int)(f2bf(r[0]) | (f2bf(r[1]) << 16));
            pk.y = (int)(f2bf(r[2]) | (f2bf(r[3]) << 16));
            pk.z = (int)(f2bf(r[4]) | (f2bf(r[5]) << 16));
            pk.w = (int)(f2bf(r[6]) | (f2bf(r[7]) << 16));
            *(i32x4*)(lds + erow * FSTR + (((unsigned)(k * 2)) ^ eswz)) = pk;
        }
    }

    f32x4 acc[4][4];
    #pragma unroll
    for (int a = 0; a < 4; ++a)
        #pragma unroll
        for (int b = 0; b < 4; ++b) acc[a][b] = (f32x4)(0.0f);

    // feats written, slice 0 landed (encode's own loads drained vmcnt anyway)
    asm volatile("s_waitcnt vmcnt(4) lgkmcnt(0)" ::: "memory");
    __builtin_amdgcn_s_barrier();

    // ---------------- layer 1: K=640, counted-vmcnt dbuf pipeline ----------------
    #pragma unroll
    for (int ks = 0; ks < NK1; ++ks) {
        const unsigned char* wb = (ks & 1) ? ldsw1 : ldsw0;
        bf16x8 wfr[4], af[4];
        #pragma unroll
        for (int cf = 0; cf < 4; ++cf)
            wfr[cf] = *(const bf16x8*)(wb + (wcol + cf * 16 + l15) * 64 + l4 * 16);
        #pragma unroll
        for (int rf = 0; rf < 4; ++rf)
            af[rf] = *(const bf16x8*)(lds + (rf * 16 + l15) * FSTR +
                        (((unsigned)(ks * 64 + l4 * 16)) ^ swz));
        asm volatile("s_waitcnt lgkmcnt(0)" ::: "memory");  // frags in regs
        __builtin_amdgcn_s_barrier();                        // buf[ks&1] free
        if (ks + 2 < NK1)
            stage_w(w1b, 640, ks + 2, (ks & 1) ? ldsw1 : ldsw0, wave, lane);
        __builtin_amdgcn_s_setprio(1);
        #pragma unroll
        for (int cf = 0; cf < 4; ++cf)
            #pragma unroll
            for (int rf = 0; rf < 4; ++rf)
                acc[rf][cf] = __builtin_amdgcn_mfma_f32_16x16x32_bf16(
                    wfr[cf], af[rf], acc[rf][cf], 0, 0, 0);
        __builtin_amdgcn_s_setprio(0);
        if (ks < NK1 - 2) asm volatile("s_waitcnt vmcnt(4)" ::: "memory");
        else              asm volatile("s_waitcnt vmcnt(0)" ::: "memory");
        __builtin_amdgcn_s_barrier();                        // slice ks+1 visible
    }

    // ---------------- bias + leaky -> h (bf16, 8B LDS writes) ----------------
    #pragma unroll
    for (int cf = 0; cf < 4; ++cf) {
        const int colb = wcol + cf * 16 + l4 * 4;
        const f32x4 bb = *(const f32x4*)(b1 + colb);
        #pragma unroll
        for (int rf = 0; rf < 4; ++rf) {
            const int row = rf * 16 + l15;
            float h0 = acc[rf][cf][0] + bb[0];
            float h1 = acc[rf][cf][1] + bb[1];
            float h2 = acc[rf][cf][2] + bb[2];
            float h3 = acc[rf][cf][3] + bb[3];
            h0 = (h0 >= 0.f) ? h0 : 0.01f * h0;
            h1 = (h1 >= 0.f) ? h1 : 0.01f * h1;
            h2 = (h2 >= 0.f) ? h2 : 0.01f * h2;
            h3 = (h3 >= 0.f) ? h3 : 0.01f * h3;
            u32x2 pk;
            pk.x = f2bf(h0) | (f2bf(h1) << 16);
            pk.y = f2bf(h2) | (f2bf(h3) << 16);
            *(u32x2*)(lds + row * HSTR + (((unsigned)(colb * 2)) ^ swz)) = pk;
        }
    }

    // issue W2 slices 0,1 — cover under the epilogue + barrier
    stage_w(w2b, 512, 0, ldsw0, wave, lane);
    stage_w(w2b, 512, 1, ldsw1, wave, lane);

    #pragma unroll
    for (int a = 0; a < 4; ++a)
        #pragma unroll
        for (int b = 0; b < 4; ++b) acc[a][b] = (f32x4)(0.0f);

    asm volatile("s_waitcnt vmcnt(4) lgkmcnt(0)" ::: "memory");  // slice0 + h-writes done
    __builtin_amdgcn_s_barrier();

    // ---------------- layer 2: K=512, same pipeline ----------------
    #pragma unroll
    for (int ks = 0; ks < NK2; ++ks) {
        const unsigned char* wb = (ks & 1) ? ldsw1 : ldsw0;
        bf16x8 wfr[4], hf[4];
        #pragma unroll
        for (int cf = 0; cf < 4; ++cf)
            wfr[cf] = *(const bf16x8*)(wb + (wcol + cf * 16 + l15) * 64 + l4 * 16);
        #pragma unroll
        for (int rf = 0; rf < 4; ++rf)
            hf[rf] = *(const bf16x8*)(lds + (rf * 16 + l15) * HSTR +
                        (((unsigned)(ks * 64 + l4 * 16)) ^ swz));
        asm volatile("s_waitcnt lgkmcnt(0)" ::: "memory");
        __builtin_amdgcn_s_barrier();
        if (ks + 2 < NK2)
            stage_w(w2b, 512, ks + 2, (ks & 1) ? ldsw1 : ldsw0, wave, lane);
        __builtin_amdgcn_s_setprio(1);
        #pragma unroll
        for (int cf = 0; cf < 4; ++cf)
            #pragma unroll
            for (int rf = 0; rf < 4; ++rf)
                acc[rf][cf] = __builtin_amdgcn_mfma_f32_16x16x32_bf16(
                    wfr[cf], hf[rf], acc[rf][cf], 0, 0, 0);
        __builtin_amdgcn_s_setprio(0);
        if (ks < NK2 - 2) asm volatile("s_waitcnt vmcnt(4)" ::: "memory");
        else              asm volatile("s_waitcnt vmcnt(0)" ::: "memory");
        __builtin_amdgcn_s_barrier();
    }

    // ---------------- epilogue: bias + float4 stores ----------------
    #pragma unroll
    for (int cf = 0; cf < 4; ++cf) {
        const int colb = wcol + cf * 16 + l4 * 4;
        const f32x4 bb = *(const f32x4*)(b2 + colb);
        #pragma unroll
        for (int rf = 0; rf < 4; ++rf) {
            const int row = rowbase + rf * 16 + l15;
            f32x4 o = acc[rf][cf] + bb;
            *(f32x4*)(out + row * 512 + colb) = o;
        }
    }
}

extern "C" void kernel_launch(void* const* d_in, const int* in_sizes, int n_in,
                              void* d_out, int out_size, void* d_ws, size_t ws_size,
                              hipStream_t stream)
{
    (void)in_sizes; (void)n_in; (void)out_size; (void)ws_size;
    const float* pf  = (const float*)d_in[0];
    const float* pt  = (const float*)d_in[1];
    const float* nm  = (const float*)d_in[2];
    const float* Wsx = (const float*)d_in[3];
    const float* bsx = (const float*)d_in[4];
    const float* Wcx = (const float*)d_in[5];
    const float* bcx = (const float*)d_in[6];
    const float* Wsy = (const float*)d_in[7];
    const float* bsy = (const float*)d_in[8];
    const float* Wcy = (const float*)d_in[9];
    const float* bcy = (const float*)d_in[10];
    const float* Wn  = (const float*)d_in[11];
    const float* bn  = (const float*)d_in[12];
    const float* W1  = (const float*)d_in[13];
    const float* b1  = (const float*)d_in[14];
    const float* W2  = (const float*)d_in[15];
    const float* b2  = (const float*)d_in[16];

    unsigned char* ws = (unsigned char*)d_ws;
    unsigned short* w1b = (unsigned short*)(ws);
    unsigned short* w2b = (unsigned short*)(ws + 512 * 640 * 2);
    float* wf  = (float*)(ws + 512 * 640 * 2 + 512 * 512 * 2);
    float* bfv = (float*)(ws + 512 * 640 * 2 + 512 * 512 * 2 + 640 * 4);

    const int prep_threads = 512 * 640 + 512 * 512;
    prep_kernel<<<(prep_threads + 255) / 256, 256, 0, stream>>>(
        W1, W2, Wsx, bsx, Wcx, bcx, Wsy, bsy, Wcy, bcy, Wn, bn, w1b, w2b, wf, bfv);

    mlp_kernel<<<NROWS / BM, 512, 0, stream>>>(
        pf, pt, nm, w1b, w2b, wf, bfv, b1, b2, (float*)d_out);
}

// Round 4
// 278.964 us; speedup vs baseline: 1.4552x; 1.0647x over previous
//
#include <hip/hip_runtime.h>
#include <stdint.h>

#define NROWS 131072
#define BM 128
#define NK1 20
#define NK2 16
#define FSTR 1280
#define HSTR 1024

typedef __attribute__((ext_vector_type(8))) short bf16x8;
typedef __attribute__((ext_vector_type(4))) float f32x4;
typedef __attribute__((ext_vector_type(4))) int i32x4;
typedef __attribute__((ext_vector_type(2))) unsigned int u32x2;

__device__ __forceinline__ unsigned f2bf(float x) {
    union { float f; unsigned u; } v; v.f = x;
    unsigned r = v.u + 0x7FFFu + ((v.u >> 16) & 1u);
    return r >> 16;
}

// ws layout:
// [0, 655360)            W1 bf16 [512][640]
// [655360, 1179648)      W2 bf16 [512][512]
// [1179648, +2560)       wf[640] f32 (encode weights, cos folded to sin)
// [1182208, +2560)       bfv[640] f32 (encode biases, +pi/2 for cos)

__global__ void prep_kernel(
    const float* __restrict__ W1, const float* __restrict__ W2,
    const float* __restrict__ Wsx, const float* __restrict__ bsx,
    const float* __restrict__ Wcx, const float* __restrict__ bcx,
    const float* __restrict__ Wsy, const float* __restrict__ bsy,
    const float* __restrict__ Wcy, const float* __restrict__ bcy,
    const float* __restrict__ Wn, const float* __restrict__ bn,
    unsigned short* __restrict__ w1b, unsigned short* __restrict__ w2b,
    float* __restrict__ wf, float* __restrict__ bfv)
{
    int i = blockIdx.x * blockDim.x + threadIdx.x;
    const int n1 = 512 * 640;
    const int n2 = 512 * 512;
    if (i < n1) w1b[i] = (unsigned short)f2bf(W1[i]);
    else if (i < n1 + n2) w2b[i - n1] = (unsigned short)f2bf(W2[i - n1]);
    if (i < 640) {
        const float HPI = 1.57079632679489662f;
        float w, b;
        if (i < 512) {
            int j = i & 63, q = (i >> 6) & 3;
            if      (q == 0) { w = Wsx[j]; b = bsx[j]; }
            else if (q == 1) { w = Wcx[j]; b = bcx[j] + HPI; }
            else if (q == 2) { w = Wsy[j]; b = bsy[j]; }
            else             { w = Wcy[j]; b = bcy[j] + HPI; }
        } else { w = Wn[i - 512]; b = bn[i - 512]; }
        wf[i] = w; bfv[i] = b;
    }
}

// LDS: feats [128][640] bf16, stride 1280 B, byte-XOR ((row&7)<<4)  = 163840 B
//      h     [128][512] bf16, stride 1024 B, same XOR (aliased at base)

__global__ __launch_bounds__(512, 2) void mlp_kernel(
    const float* __restrict__ pf, const float* __restrict__ pt,
    const float* __restrict__ nm,
    const unsigned short* __restrict__ w1b,
    const unsigned short* __restrict__ w2b,
    const float* __restrict__ wf, const float* __restrict__ bfv,
    const float* __restrict__ b1, const float* __restrict__ b2,
    float* __restrict__ out)
{
    __shared__ __align__(16) unsigned char lds[163840];

    const int tid  = threadIdx.x;
    const int lane = tid & 63;
    const int wave = tid >> 6;          // 0..7, each owns 64 output cols
    const int l15  = lane & 15;
    const int l4   = lane >> 4;         // 0..3
    const int rowbase = blockIdx.x * BM;
    const int wcol = wave * 64;
    const unsigned swz = (unsigned)((l15 & 7) << 4);

    // A-operand (weights): row = out col (wcol+cf*16+l15), k = ks*32 + l4*8
    const unsigned short* w1p = w1b + (wcol + l15) * 640 + l4 * 8;
    const unsigned short* w2p = w2b + (wcol + l15) * 512 + l4 * 8;

    // depth-4 rotating register buffers for W fragments
    bf16x8 wb[4][4];
    #pragma unroll
    for (int t = 0; t < 4; ++t)
        #pragma unroll
        for (int cf = 0; cf < 4; ++cf)
            wb[t][cf] = *(const bf16x8*)(w1p + cf * (16 * 640) + t * 32);

    // ---------------- encode: 4 threads/row, 160 feats each ----------------
    {
        const int erow = tid >> 2;          // 0..127
        const int esub = tid & 3;
        const int grow = rowbase + erow;
        const float v0 = pf[grow * 2 + 0];
        const float v1 = pf[grow * 2 + 1];
        const float v2 = pt[grow * 2 + 0];
        const float v3 = pt[grow * 2 + 1];
        const float v4 = nm[grow];
        const unsigned eswz = (unsigned)((erow & 7) << 4);
        const int k0 = esub * 160;
        #pragma unroll
        for (int j = 0; j < 20; ++j) {
            const int k = k0 + j * 8;
            const int op = (k >= 512);
            const int srcsel = op ? 4 : (((k >> 8) << 1) | ((k >> 7) & 1));
            const float xv = (srcsel == 0) ? v0 : (srcsel == 1) ? v1 :
                             (srcsel == 2) ? v2 : (srcsel == 3) ? v3 : v4;
            const f32x4 w0 = *(const f32x4*)(wf + k);
            const f32x4 w1v = *(const f32x4*)(wf + k + 4);
            const f32x4 c0 = *(const f32x4*)(bfv + k);
            const f32x4 c1 = *(const f32x4*)(bfv + k + 4);
            float r[8];
            #pragma unroll
            for (int t = 0; t < 4; ++t) {
                float a0 = fmaf(xv, w0[t], c0[t]);
                float a1 = fmaf(xv, w1v[t], c1[t]);
                r[t]     = op ? a0 : __sinf(a0);
                r[t + 4] = op ? a1 : __sinf(a1);
            }
            i32x4 pk;
            pk.x = (int)(f2bf(r[0]) | (f2bf(r[1]) << 16));
            pk.y = (int)(f2bf(r[2]) | (f2bf(r[3]) << 16));
            pk.z = (int)(f2bf(r[4]) | (f2bf(r[5]) << 16));
            pk.w = (int)(f2bf(r[6]) | (f2bf(r[7]) << 16));
            *(i32x4*)(lds + erow * FSTR + (((unsigned)(k * 2)) ^ eswz)) = pk;
        }
    }

    f32x4 acc[8][4];
    #pragma unroll
    for (int a = 0; a < 8; ++a)
        #pragma unroll
        for (int b = 0; b < 4; ++b) acc[a][b] = (f32x4)(0.0f);

    __syncthreads();

    // ---------------- layer 1: K=640, free-running depth-4 pipeline ----------------
    for (int ks2 = 0; ks2 < 5; ++ks2) {
        const int base = ks2 * 4;
        #pragma unroll
        for (int t = 0; t < 4; ++t) {
            const int ks = base + t;
            #pragma unroll
            for (int rf = 0; rf < 8; ++rf) {
                bf16x8 af = *(const bf16x8*)(lds + (rf * 16 + l15) * FSTR +
                              (((unsigned)(ks * 64 + l4 * 16)) ^ swz));
                #pragma unroll
                for (int cf = 0; cf < 4; ++cf)
                    acc[rf][cf] = __builtin_amdgcn_mfma_f32_16x16x32_bf16(
                        wb[t][cf], af, acc[rf][cf], 0, 0, 0);
            }
            if (ks + 4 < NK1) {
                #pragma unroll
                for (int cf = 0; cf < 4; ++cf)
                    wb[t][cf] = *(const bf16x8*)(w1p + cf * (16 * 640) + (ks + 4) * 32);
            }
        }
    }

    // prologue W2 loads — latency hidden under h-epilogue + barrier
    #pragma unroll
    for (int t = 0; t < 4; ++t)
        #pragma unroll
        for (int cf = 0; cf < 4; ++cf)
            wb[t][cf] = *(const bf16x8*)(w2p + cf * (16 * 512) + t * 32);

    __syncthreads();   // all feats reads done; h may alias feats

    // ---------------- bias + leaky -> h (bf16, 8B LDS writes) ----------------
    #pragma unroll
    for (int cf = 0; cf < 4; ++cf) {
        const int colb = wcol + cf * 16 + l4 * 4;
        const f32x4 bb = *(const f32x4*)(b1 + colb);
        #pragma unroll
        for (int rf = 0; rf < 8; ++rf) {
            const int row = rf * 16 + l15;
            float h0 = acc[rf][cf][0] + bb[0];
            float h1 = acc[rf][cf][1] + bb[1];
            float h2 = acc[rf][cf][2] + bb[2];
            float h3 = acc[rf][cf][3] + bb[3];
            h0 = (h0 >= 0.f) ? h0 : 0.01f * h0;
            h1 = (h1 >= 0.f) ? h1 : 0.01f * h1;
            h2 = (h2 >= 0.f) ? h2 : 0.01f * h2;
            h3 = (h3 >= 0.f) ? h3 : 0.01f * h3;
            u32x2 pk;
            pk.x = f2bf(h0) | (f2bf(h1) << 16);
            pk.y = f2bf(h2) | (f2bf(h3) << 16);
            *(u32x2*)(lds + row * HSTR + (((unsigned)(colb * 2)) ^ swz)) = pk;
        }
    }

    #pragma unroll
    for (int a = 0; a < 8; ++a)
        #pragma unroll
        for (int b = 0; b < 4; ++b) acc[a][b] = (f32x4)(0.0f);

    __syncthreads();

    // ---------------- layer 2: K=512, same pipeline ----------------
    for (int ks2 = 0; ks2 < 4; ++ks2) {
        const int base = ks2 * 4;
        #pragma unroll
        for (int t = 0; t < 4; ++t) {
            const int ks = base + t;
            #pragma unroll
            for (int rf = 0; rf < 8; ++rf) {
                bf16x8 hf = *(const bf16x8*)(lds + (rf * 16 + l15) * HSTR +
                              (((unsigned)(ks * 64 + l4 * 16)) ^ swz));
                #pragma unroll
                for (int cf = 0; cf < 4; ++cf)
                    acc[rf][cf] = __builtin_amdgcn_mfma_f32_16x16x32_bf16(
                        wb[t][cf], hf, acc[rf][cf], 0, 0, 0);
            }
            if (ks + 4 < NK2) {
                #pragma unroll
                for (int cf = 0; cf < 4; ++cf)
                    wb[t][cf] = *(const bf16x8*)(w2p + cf * (16 * 512) + (ks + 4) * 32);
            }
        }
    }

    // ---------------- epilogue: bias + float4 stores ----------------
    #pragma unroll
    for (int cf = 0; cf < 4; ++cf) {
        const int colb = wcol + cf * 16 + l4 * 4;
        const f32x4 bb = *(const f32x4*)(b2 + colb);
        #pragma unroll
        for (int rf = 0; rf < 8; ++rf) {
            const int row = rowbase + rf * 16 + l15;
            f32x4 o = acc[rf][cf] + bb;
            *(f32x4*)(out + row * 512 + colb) = o;
        }
    }
}

extern "C" void kernel_launch(void* const* d_in, const int* in_sizes, int n_in,
                              void* d_out, int out_size, void* d_ws, size_t ws_size,
                              hipStream_t stream)
{
    (void)in_sizes; (void)n_in; (void)out_size; (void)ws_size;
    const float* pf  = (const float*)d_in[0];
    const float* pt  = (const float*)d_in[1];
    const float* nm  = (const float*)d_in[2];
    const float* Wsx = (const float*)d_in[3];
    const float* bsx = (const float*)d_in[4];
    const float* Wcx = (const float*)d_in[5];
    const float* bcx = (const float*)d_in[6];
    const float* Wsy = (const float*)d_in[7];
    const float* bsy = (const float*)d_in[8];
    const float* Wcy = (const float*)d_in[9];
    const float* bcy = (const float*)d_in[10];
    const float* Wn  = (const float*)d_in[11];
    const float* bn  = (const float*)d_in[12];
    const float* W1  = (const float*)d_in[13];
    const float* b1  = (const float*)d_in[14];
    const float* W2  = (const float*)d_in[15];
    const float* b2  = (const float*)d_in[16];

    unsigned char* ws = (unsigned char*)d_ws;
    unsigned short* w1b = (unsigned short*)(ws);
    unsigned short* w2b = (unsigned short*)(ws + 512 * 640 * 2);
    float* wf  = (float*)(ws + 512 * 640 * 2 + 512 * 512 * 2);
    float* bfv = (float*)(ws + 512 * 640 * 2 + 512 * 512 * 2 + 640 * 4);

    const int prep_threads = 512 * 640 + 512 * 512;
    prep_kernel<<<(prep_threads + 255) / 256, 256, 0, stream>>>(
        W1, W2, Wsx, bsx, Wcx, bcx, Wsy, bsy, Wcy, bcy, Wn, bn, w1b, w2b, wf, bfv);

    mlp_kernel<<<NROWS / BM, 512, 0, stream>>>(
        pf, pt, nm, w1b, w2b, wf, bfv, b1, b2, (float*)d_out);
}